// Round 2
// baseline (2250.116 us; speedup 1.0000x reference)
//
#include <hip/hip_runtime.h>

typedef unsigned short u16;
typedef unsigned int   u32;
typedef __attribute__((ext_vector_type(8))) unsigned short u16x8;
typedef __attribute__((ext_vector_type(8))) short bf16x8;
typedef __attribute__((ext_vector_type(4))) float f32x4;

__device__ __forceinline__ float b2f(u16 u) { return __uint_as_float(((u32)u) << 16); }
__device__ __forceinline__ u16 f2b(float f) {
  u32 u = __float_as_uint(f);
  return (u16)((u + 0x7FFFu + ((u >> 16) & 1u)) >> 16);   // RNE
}

// ---------------- weight prep: transpose to (N x K) row-major + cvt bf16 ----
// wt layout (elements):
//   [0..786432)        : WqT[3]   (3 x 512x512), WqT[i] at i*262144
//   [786432..2359296)  : (WkT,WvT)[3] pairs: kv_i at 786432+i*524288 (K rows 0..511, V rows 512..1023)
//   [2359296..2883584) : f0T (1024x512)
//   [2883584..3407872) : f1T (1024x512)
__global__ __launch_bounds__(256) void prep_w(const float* __restrict__ Wq,
    const float* __restrict__ Wk, const float* __restrict__ Wv,
    const float* __restrict__ f0, const float* __restrict__ f1,
    u16* __restrict__ wt) {
  int t = blockIdx.x * 256 + threadIdx.x;
  float v;
  if (t < 786432) {
    int i = t >> 18, r = t & 262143, n = r >> 9, k = r & 511;
    v = Wq[(size_t)(i << 18) + k * 512 + n];
  } else if (t < 2359296) {
    int r = t - 786432, i = r >> 19, r2 = r & 524287;
    int n = (r2 >> 9) & 511, k = r2 & 511;
    v = ((r2 >> 18) ? Wv : Wk)[(size_t)(i << 18) + k * 512 + n];
  } else if (t < 2883584) {
    int r = t - 2359296, n = r >> 9, k = r & 511;
    v = f0[(size_t)k * 1024 + n];
  } else {
    int r = t - 2883584, n = r >> 9, k = r & 511;
    v = f1[(size_t)k * 1024 + n];
  }
  wt[t] = f2b(v);
}

// ---------------- LayerNorm (fp32 in) -> xn bf16, xb bf16(raw) --------------
__global__ __launch_bounds__(256) void ln_f32(const float* __restrict__ x,
    const float* __restrict__ g, const float* __restrict__ bta,
    u16* __restrict__ xn, u16* __restrict__ xb) {
  int row = (blockIdx.x << 2) + (threadIdx.x >> 6);
  int lane = threadIdx.x & 63;
  const float* xr = x + (size_t)row * 512 + (lane << 3);
  float4 a = *(const float4*)xr;
  float4 c = *(const float4*)(xr + 4);
  float v[8] = {a.x, a.y, a.z, a.w, c.x, c.y, c.z, c.w};
  float s = 0.f, s2 = 0.f;
#pragma unroll
  for (int j = 0; j < 8; ++j) { s += v[j]; s2 += v[j] * v[j]; }
  for (int off = 32; off; off >>= 1) { s += __shfl_xor(s, off); s2 += __shfl_xor(s2, off); }
  float mean = s * (1.f / 512.f);
  float var = s2 * (1.f / 512.f) - mean * mean;
  float rs = rsqrtf(var + 1e-5f);
  const float* gp = g + (lane << 3);
  const float* bp = bta + (lane << 3);
  u16x8 pb, pn;
#pragma unroll
  for (int j = 0; j < 8; ++j) {
    pb[j] = f2b(v[j]);
    pn[j] = f2b((v[j] - mean) * rs * gp[j] + bp[j]);
  }
  *(u16x8*)(xb + (size_t)row * 512 + (lane << 3)) = pb;
  *(u16x8*)(xn + (size_t)row * 512 + (lane << 3)) = pn;
}

// ---------------- LayerNorm (bf16 in) -> bf16 out ---------------------------
__global__ __launch_bounds__(256) void ln_b16(const u16* __restrict__ xin,
    const float* __restrict__ g, const float* __restrict__ bta,
    u16* __restrict__ xout) {
  int row = (blockIdx.x << 2) + (threadIdx.x >> 6);
  int lane = threadIdx.x & 63;
  u16x8 u = *(const u16x8*)(xin + (size_t)row * 512 + (lane << 3));
  float v[8];
#pragma unroll
  for (int j = 0; j < 8; ++j) v[j] = b2f(u[j]);
  float s = 0.f, s2 = 0.f;
#pragma unroll
  for (int j = 0; j < 8; ++j) { s += v[j]; s2 += v[j] * v[j]; }
  for (int off = 32; off; off >>= 1) { s += __shfl_xor(s, off); s2 += __shfl_xor(s2, off); }
  float mean = s * (1.f / 512.f);
  float var = s2 * (1.f / 512.f) - mean * mean;
  float rs = rsqrtf(var + 1e-5f);
  const float* gp = g + (lane << 3);
  const float* bp = bta + (lane << 3);
  u16x8 pn;
#pragma unroll
  for (int j = 0; j < 8; ++j) pn[j] = f2b((v[j] - mean) * rs * gp[j] + bp[j]);
  *(u16x8*)(xout + (size_t)row * 512 + (lane << 3)) = pn;
}

// ---------------- GEMM: C(MxN bf16) = A(Mx512 bf16) * Bt(Nx512 bf16)^T ------
// m97-style 128x128 tile, BK=64, 4 waves, global_load_lds 16B staging.
template <bool GELU>
__global__ __launch_bounds__(256, 2) void gemm_bt(const u16* __restrict__ A,
    const u16* __restrict__ Bt, u16* __restrict__ C,
    const float* __restrict__ bias, int M, int N) {
  __shared__ __align__(16) u16 As[128 * 64];
  __shared__ __align__(16) u16 Bs[128 * 64];
  int tid = threadIdx.x;
  int w = tid >> 6, lane = tid & 63;
  int m0 = blockIdx.y << 7, n0 = blockIdx.x << 7;
  int wm = (w & 1) << 6, wn = (w >> 1) << 6;
  f32x4 acc[4][4] = {};
  const int r_off = lane >> 3;        // 0..7 (row within 8-row chunk)
  const int k_off = (lane & 7) << 3;  // 0..56 (bf16 col)
  for (int kt = 0; kt < 8; ++kt) {
    __syncthreads();
#pragma unroll
    for (int j = 0; j < 4; ++j) {
      int q = (w << 2) + j;  // chunk 0..15, 8 rows each
      const u16* gA = A + (size_t)(m0 + (q << 3) + r_off) * 512 + (kt << 6) + k_off;
      __builtin_amdgcn_global_load_lds(
          (const __attribute__((address_space(1))) u32*)gA,
          (__attribute__((address_space(3))) u32*)(As + (q << 9)), 16, 0, 0);
      const u16* gB = Bt + (size_t)(n0 + (q << 3) + r_off) * 512 + (kt << 6) + k_off;
      __builtin_amdgcn_global_load_lds(
          (const __attribute__((address_space(1))) u32*)gB,
          (__attribute__((address_space(3))) u32*)(Bs + (q << 9)), 16, 0, 0);
    }
    asm volatile("s_waitcnt vmcnt(0)" ::: "memory");
    __syncthreads();
#pragma unroll
    for (int kk = 0; kk < 2; ++kk) {
      int ko = (kk << 5) + ((lane >> 4) << 3);
      bf16x8 af[4], bfr[4];
#pragma unroll
      for (int mi = 0; mi < 4; ++mi)
        af[mi] = *(const bf16x8*)(As + (wm + (mi << 4) + (lane & 15)) * 64 + ko);
#pragma unroll
      for (int ni = 0; ni < 4; ++ni)
        bfr[ni] = *(const bf16x8*)(Bs + (wn + (ni << 4) + (lane & 15)) * 64 + ko);
#pragma unroll
      for (int mi = 0; mi < 4; ++mi)
#pragma unroll
        for (int ni = 0; ni < 4; ++ni)
          acc[mi][ni] = __builtin_amdgcn_mfma_f32_16x16x32_bf16(af[mi], bfr[ni], acc[mi][ni], 0, 0, 0);
    }
  }
  int cr = (lane >> 4) << 2, cc = lane & 15;
#pragma unroll
  for (int mi = 0; mi < 4; ++mi) {
#pragma unroll
    for (int ni = 0; ni < 4; ++ni) {
      int col = n0 + wn + (ni << 4) + cc;
      float bv = 0.f;
      if (GELU) bv = bias[col];
#pragma unroll
      for (int j = 0; j < 4; ++j) {
        int row = m0 + wm + (mi << 4) + cr + j;
        float v = acc[mi][ni][j];
        if (GELU) { v += bv; v = 0.5f * v * (1.f + erff(v * 0.70710678118f)); }
        C[(size_t)row * N + col] = f2b(v);
      }
    }
  }
}

// ---------------- attention: per-batch block ---------------------------------
// Q: (nb*25, 512) bf16; KV: (nb*NKV, 1024) bf16 [K cols 0..511, V 512..1023]
// thread t: head h = t>>5, query row n = t&31 (n<25). out = [x +] (1/3)*softmax(QK^T/8)V
template <int NKV, bool INIT>
__global__ __launch_bounds__(256) void attn(const u16* __restrict__ Q,
    const u16* __restrict__ KV, const float* __restrict__ x, float* __restrict__ out) {
  __shared__ __align__(16) u16 KVl[NKV * 1024];
  int b = blockIdx.x, tid = threadIdx.x;
  const u16* kvb = KV + (size_t)b * NKV * 1024;
  for (int e = tid * 8; e < NKV * 1024; e += 2048)
    *(u16x8*)(KVl + e) = *(const u16x8*)(kvb + e);
  __syncthreads();
  int h = tid >> 5, n = tid & 31;
  if (n < 25) {
    const u16* qr = Q + (size_t)(b * 25 + n) * 512 + (h << 6);
    float q[64];
#pragma unroll
    for (int i = 0; i < 8; ++i) {
      u16x8 u = *(const u16x8*)(qr + (i << 3));
#pragma unroll
      for (int j = 0; j < 8; ++j) q[i * 8 + j] = b2f(u[j]);
    }
    float s[NKV];
    float mx = -1e30f;
#pragma unroll
    for (int m = 0; m < NKV; ++m) {
      const u16* kr = KVl + m * 1024 + (h << 6);
      float d = 0.f;
#pragma unroll
      for (int i = 0; i < 8; ++i) {
        u16x8 u = *(const u16x8*)(kr + (i << 3));
#pragma unroll
        for (int j = 0; j < 8; ++j) d += q[i * 8 + j] * b2f(u[j]);
      }
      s[m] = d * 0.125f;
      mx = fmaxf(mx, s[m]);
    }
    float sum = 0.f;
#pragma unroll
    for (int m = 0; m < NKV; ++m) { s[m] = __expf(s[m] - mx); sum += s[m]; }
    float o[64] = {};
#pragma unroll
    for (int m = 0; m < NKV; ++m) {
      float a = s[m];
      const u16* vr = KVl + m * 1024 + 512 + (h << 6);
#pragma unroll
      for (int i = 0; i < 8; ++i) {
        u16x8 u = *(const u16x8*)(vr + (i << 3));
#pragma unroll
        for (int j = 0; j < 8; ++j) o[i * 8 + j] += a * b2f(u[j]);
      }
    }
    float sc = (1.f / sum) * (1.f / 3.f);
    float* orow = out + (size_t)(b * 25 + n) * 512 + (h << 6);
    const float* xrow = x + (size_t)(b * 25 + n) * 512 + (h << 6);
#pragma unroll
    for (int i = 0; i < 16; ++i) {
      float4 r;
      r.x = o[i * 4 + 0] * sc; r.y = o[i * 4 + 1] * sc;
      r.z = o[i * 4 + 2] * sc; r.w = o[i * 4 + 3] * sc;
      if (INIT) {
        float4 xv = *(const float4*)(xrow + i * 4);
        r.x += xv.x; r.y += xv.y; r.z += xv.z; r.w += xv.w;
      } else {
        float4 pv = *(const float4*)(orow + i * 4);
        r.x += pv.x; r.y += pv.y; r.z += pv.z; r.w += pv.w;
      }
      *(float4*)(orow + i * 4) = r;
    }
  }
}

// ---------------- pool: fc2 + softmax + S^T * l_feat ------------------------
// h: (nb*NIN, 1024) bf16 (gelu'd fc1 out); lf: (nb*NIN, 512) bf16 raw l_feat
// w2: (1024, NOUT) fp32; out lout: (nb*NOUT, 512) bf16
template <int NIN, int NOUT>
__global__ __launch_bounds__(256) void pool(const u16* __restrict__ h,
    const u16* __restrict__ lf, const float* __restrict__ w2,
    const float* __restrict__ b2, u16* __restrict__ lout) {
  __shared__ __align__(16) float W2l[1024 * NOUT];
  __shared__ __align__(16) u16 Xl[NIN * 512];
  __shared__ __align__(16) float Sl[NIN * NOUT];
  int b = blockIdx.x, tid = threadIdx.x;
  for (int e = tid; e < 1024 * NOUT; e += 256) W2l[e] = w2[e];
  for (int e = tid * 8; e < NIN * 512; e += 2048)
    *(u16x8*)(Xl + e) = *(const u16x8*)(lf + (size_t)b * NIN * 512 + e);
  __syncthreads();
  if (tid < NIN * 8) {
    int nn = tid >> 3, sub = tid & 7;
    float p[NOUT] = {};
    const u16* hr = h + (size_t)(b * NIN + nn) * 1024;
    for (int cc = 0; cc < 128; ++cc) {
      int c = sub + (cc << 3);     // stride-8 so 8 subs hit distinct LDS banks
      float hv = b2f(hr[c]);
#pragma unroll
      for (int s2 = 0; s2 < NOUT; ++s2) p[s2] += hv * W2l[c * NOUT + s2];
    }
#pragma unroll
    for (int s2 = 0; s2 < NOUT; ++s2) {
      p[s2] += __shfl_down(p[s2], 4, 8);
      p[s2] += __shfl_down(p[s2], 2, 8);
      p[s2] += __shfl_down(p[s2], 1, 8);
    }
    if (sub == 0) {
      float mx = -1e30f;
#pragma unroll
      for (int s2 = 0; s2 < NOUT; ++s2) { p[s2] += b2[s2]; mx = fmaxf(mx, p[s2]); }
      float sum = 0.f;
#pragma unroll
      for (int s2 = 0; s2 < NOUT; ++s2) { p[s2] = __expf(p[s2] - mx); sum += p[s2]; }
      float inv = 1.f / sum;
#pragma unroll
      for (int s2 = 0; s2 < NOUT; ++s2) Sl[nn * NOUT + s2] = p[s2] * inv;
    }
  }
  __syncthreads();
  int c0 = tid << 1;
#pragma unroll
  for (int s2 = 0; s2 < NOUT; ++s2) {
    float a0 = 0.f, a1 = 0.f;
#pragma unroll
    for (int nn = 0; nn < NIN; ++nn) {
      float wv = Sl[nn * NOUT + s2];
      a0 += wv * b2f(Xl[nn * 512 + c0]);
      a1 += wv * b2f(Xl[nn * 512 + c0 + 1]);
    }
    u32 pk = (u32)f2b(a0) | ((u32)f2b(a1) << 16);
    *(u32*)(lout + (size_t)(b * NOUT + s2) * 512 + c0) = pk;
  }
}

// ---------------- launcher ---------------------------------------------------
extern "C" void kernel_launch(void* const* d_in, const int* in_sizes, int n_in,
                              void* d_out, int out_size, void* d_ws, size_t ws_size,
                              hipStream_t stream) {
  const float* src = (const float*)d_in[0];
  // d_in[1] spatial_relation: unused (dead in reference output math)
  const float* g    = (const float*)d_in[2];
  const float* bt   = (const float*)d_in[3];
  const float* Wq   = (const float*)d_in[4];
  const float* Wk   = (const float*)d_in[5];
  const float* Wv   = (const float*)d_in[6];
  const float* f0w  = (const float*)d_in[7];
  const float* f0b  = (const float*)d_in[8];
  const float* f0w2 = (const float*)d_in[9];
  const float* f0b2 = (const float*)d_in[10];
  const float* f1w  = (const float*)d_in[11];
  const float* f1b  = (const float*)d_in[12];
  const float* f1w2 = (const float*)d_in[13];
  const float* f1b2 = (const float*)d_in[14];
  float* out = (float*)d_out;
  char* ws = (char*)d_ws;

  // workspace layout (bytes), peak ~503 MB:
  //  wt   0           ..   6,815,744
  //  xn   6,815,744   .. 111,673,344
  //  xb   111,673,344 .. 216,530,944
  //  qb   216,530,944 .. 321,388,544  (later also hosts l2 @ +0, kn2 @ +29,360,128)
  //  B1   321,388,544 .. 426,246,144  (kv0 half / h0 half / kv1 / h1 / kv2)
  //  l1   426,246,144 .. 476,577,792
  //  kn1  476,577,792 .. 526,909,440
  u16* wt  = (u16*)(ws + 0);
  u16* xn  = (u16*)(ws + 6815744);
  u16* xb  = (u16*)(ws + 111673344);
  u16* qb  = (u16*)(ws + 216530944);
  u16* B1  = (u16*)(ws + 321388544);
  u16* l1  = (u16*)(ws + 426246144);
  u16* kn1 = (u16*)(ws + 476577792);
  u16* l2  = qb;                       // 14,680,064 elems (28 MB), alive pool1->ln
  u16* kn2 = qb + 14680064;            // 14,680,064 elems, alive ln->KV2 gemm

  prep_w<<<13312, 256, 0, stream>>>(Wq, Wk, Wv, f0w, f1w, wt);
  ln_f32<<<25600, 256, 0, stream>>>(src, g, bt, xn, xb);

  // scale 0: Q gemm full, KV gemm + attn in 2 half-slices sharing B1 (100 MB)
  gemm_bt<false><<<dim3(4, 800), 256, 0, stream>>>(xn, wt, qb, nullptr, 102400, 512);
  for (int s = 0; s < 2; ++s) {
    size_t ro = (size_t)s * 51200;   // row offset (2048 batches)
    gemm_bt<false><<<dim3(8, 400), 256, 0, stream>>>(xn + ro * 512, wt + 786432, B1, nullptr, 51200, 1024);
    attn<25, true><<<2048, 256, 0, stream>>>(qb + ro * 512, B1, src + ro * 512, out + ro * 512);
  }

  // pool 0: fc1(gelu) gemm + pool in 2 half-slices, h half lives in B1
  for (int s = 0; s < 2; ++s) {
    size_t ro = (size_t)s * 51200;
    gemm_bt<true><<<dim3(8, 400), 256, 0, stream>>>(xb + ro * 512, wt + 2359296, B1, f0b, 51200, 1024);
    pool<25, 12><<<2048, 256, 0, stream>>>(B1, xb + ro * 512, f0w2, f0b2, l1 + (size_t)s * 2048 * 12 * 512);
  }
  ln_b16<<<12288, 256, 0, stream>>>(l1, g, bt, kn1);

  // scale 1
  gemm_bt<false><<<dim3(4, 800), 256, 0, stream>>>(xn, wt + 262144, qb, nullptr, 102400, 512);
  gemm_bt<false><<<dim3(8, 384), 256, 0, stream>>>(kn1, wt + 786432 + 524288, B1, nullptr, 49152, 1024);
  attn<12, false><<<4096, 256, 0, stream>>>(qb, B1, src, out);

  // pool 1: h1 (96 MB) in B1 after attn1
  gemm_bt<true><<<dim3(8, 384), 256, 0, stream>>>(l1, wt + 2883584, B1, f1b, 49152, 1024);
  pool<12, 7><<<4096, 256, 0, stream>>>(B1, l1, f1w2, f1b2, l2);
  ln_b16<<<7168, 256, 0, stream>>>(l2, g, bt, kn2);

  // scale 2: KV gemm BEFORE Q gemm (kn2 lives in qb region; Q2 gemm clobbers it)
  gemm_bt<false><<<dim3(8, 224), 256, 0, stream>>>(kn2, wt + 786432 + 1048576, B1, nullptr, 28672, 1024);
  gemm_bt<false><<<dim3(4, 800), 256, 0, stream>>>(xn, wt + 524288, qb, nullptr, 102400, 512);
  attn<7, false><<<4096, 256, 0, stream>>>(qb, B1, src, out);
}